// Round 4
// baseline (47.148 us; speedup 1.0000x reference)
//
#include <hip/hip_runtime.h>
#include <math.h>

#define N 4096
#define BSZ 2048
#define D 128
#define NDIST 199
#define PI_F 3.14159265358979323846f

typedef __bf16 bf16x8 __attribute__((ext_vector_type(8)));
typedef float f32x4 __attribute__((ext_vector_type(4)));
typedef unsigned short u16x8 __attribute__((ext_vector_type(8)));

// cf[i] = features[i % bsz, i / bsz, :]  (view-major stacking)
__device__ __forceinline__ int rowbase(int i) {
    return (i & (BSZ - 1)) * (2 * D) + (i >> 11) * D;
}

__device__ __forceinline__ unsigned short f2bf(float x) {
    unsigned u = __float_as_uint(x);
    return (unsigned short)((u + 0x7fffu + ((u >> 16) & 1u)) >> 16);  // RNE
}

// ws layout: floats m[0..N) S1[N..2N) sumc[2N..3N) cnt[3N..4N); then bf16 cf[N][D]
__global__ void init_kernel(const float* __restrict__ feat, float* __restrict__ ws,
                            unsigned short* __restrict__ cf) {
    int t = threadIdx.x;
    int row = blockIdx.x * 16 + (t >> 4);
    int lq = t & 15;
    const float* p = feat + rowbase(row) + lq * 8;
    float4 v0 = *(const float4*)(p);
    float4 v1 = *(const float4*)(p + 4);
    float dot = v0.x * v0.x + v0.y * v0.y + v0.z * v0.z + v0.w * v0.w
              + v1.x * v1.x + v1.y * v1.y + v1.z * v1.z + v1.w * v1.w;
#pragma unroll
    for (int off = 1; off < 16; off <<= 1) dot += __shfl_xor(dot, off);

    u16x8 u;
    u[0] = f2bf(v0.x); u[1] = f2bf(v0.y); u[2] = f2bf(v0.z); u[3] = f2bf(v0.w);
    u[4] = f2bf(v1.x); u[5] = f2bf(v1.y); u[6] = f2bf(v1.z); u[7] = f2bf(v1.w);
    *(u16x8*)(cf + row * D + lq * 8) = u;

    if (lq == 0) {
        ws[row] = fminf(fmaxf(dot, -1.f), 1.f);  // rowmax = clipped diagonal
        ws[N + row] = 0.f;
        ws[2 * N + row] = 0.f;
        ws[3 * N + row] = 0.f;
    }
}

// 2048 blocks: bi in [0,64) (I tiles of 64 rows), bj in [0,32) (J tiles of 128)
__launch_bounds__(256, 8)
__global__ void pair_kernel(const unsigned short* __restrict__ cf,
                            const int* __restrict__ labels, float* __restrict__ ws) {
    __shared__ float2 tab[NDIST];
    __shared__ int labI[64];
    __shared__ float mI[64];
    __shared__ unsigned int labJ4[32];   // 128 J labels packed 4x u8

    const int t = threadIdx.x;
    const int bi = blockIdx.x >> 5;
    const int bj = blockIdx.x & 31;
    const int i0 = bi * 64, j0 = bj * 128;

    if (t < NDIST) {
        float phi = (1.0f - (float)(t - 99) / 100.0f) * PI_F;
        tab[t] = make_float2(cosf(phi), fabsf(sinf(phi)));
    }
    {
        int u = t - 64;
        if ((unsigned)u < 64u) {
            labI[u] = labels[(i0 + u) & (BSZ - 1)];
            mI[u] = ws[i0 + u];
        }
        int v = t - 128;
        if ((unsigned)v < 32u) {
            int j = j0 + v * 4;
            unsigned p0 = (unsigned)labels[j & (BSZ - 1)];
            unsigned p1 = (unsigned)labels[(j + 1) & (BSZ - 1)];
            unsigned p2 = (unsigned)labels[(j + 2) & (BSZ - 1)];
            unsigned p3 = (unsigned)labels[(j + 3) & (BSZ - 1)];
            labJ4[v] = p0 | (p1 << 8) | (p2 << 16) | (p3 << 24);
        }
    }
    __syncthreads();

    const int wid = t >> 6, lane = t & 63;
    const int wp = wid >> 1, wq = wid & 1;      // wp: I half (32 rows), wq: J half (64)
    const int lrow = lane & 15, lk = (lane >> 4) * 8;

    // SWAPPED operands: A = J rows, B = I rows -> D[row=J][col=I]
    const unsigned short* A0 = cf + (size_t)(j0 + wq * 64 + lrow) * D + lk;
    const unsigned short* B0 = cf + (size_t)(i0 + wp * 32 + lrow) * D + lk;

    f32x4 acc[4][2] = {};   // [ar: J fragment][ac: I fragment]
#pragma unroll
    for (int ks = 0; ks < 4; ++ks) {
        bf16x8 b[2];
#pragma unroll
        for (int c = 0; c < 2; ++c) b[c] = *(const bf16x8*)(B0 + c * 16 * D + ks * 32);
#pragma unroll
        for (int r = 0; r < 4; ++r) {
            bf16x8 a = *(const bf16x8*)(A0 + r * 16 * D + ks * 32);
            acc[r][0] = __builtin_amdgcn_mfma_f32_16x16x32_bf16(a, b[0], acc[r][0], 0, 0, 0);
            acc[r][1] = __builtin_amdgcn_mfma_f32_16x16x32_bf16(a, b[1], acc[r][1], 0, 0, 0);
        }
    }

    // per-lane packed J labels: jr_local = wq*64 + ar*16 + (lane>>4)*4 + rg
    const int jbl = wq * 64 + ((lane >> 4) << 2);
    unsigned int ljp[4];
#pragma unroll
    for (int ar = 0; ar < 4; ++ar) ljp[ar] = labJ4[(jbl + ar * 16) >> 2];

#pragma unroll
    for (int ac = 0; ac < 2; ++ac) {
        const int ri = wp * 32 + ac * 16 + lrow;   // I index (lane-local)
        const int gi = i0 + ri;
        const int li99 = labI[ri] + 99;
        const float m = mI[ri];
        const int dg = gi - (j0 + jbl);            // diag when dg == ar*16+rg
        float s1 = 0.f, sc = 0.f, ct = 0.f;
#pragma unroll
        for (int ar = 0; ar < 4; ++ar) {
#pragma unroll
            for (int rg = 0; rg < 4; ++rg) {
                float c = __builtin_amdgcn_fmed3f(acc[ar][ac][rg], -1.f, 1.f);
                int idx = li99 - (int)((ljp[ar] >> (8 * rg)) & 255u);
                float2 cs = tab[idx];
                float st = __builtin_amdgcn_sqrtf(fmaf(-c, c, 1.000001f));
                float nl = fmaf(c, cs.x, -st * cs.y);
                bool pos = (idx == 99);
                bool diag = (dg == ar * 16 + rg);
                float logit = pos ? (c - m) : nl;
                float e = diag ? 0.f : __expf(logit);
                float pf = (pos && !diag) ? 1.f : 0.f;
                s1 += e;
                sc = fmaf(pf, c, sc);
                ct += pf;
            }
        }
        // combine the 4 lane-groups that share gi (lane&15): xor 16, then 32
        s1 += __shfl_xor(s1, 16); s1 += __shfl_xor(s1, 32);
        sc += __shfl_xor(sc, 16); sc += __shfl_xor(sc, 32);
        ct += __shfl_xor(ct, 16); ct += __shfl_xor(ct, 32);
        if (lane < 16) {
            atomicAdd(&ws[N + gi], s1);
            atomicAdd(&ws[2 * N + gi], sc);
            atomicAdd(&ws[3 * N + gi], ct);
        }
    }
}

__global__ void final_kernel(const float* __restrict__ ws, float* __restrict__ out) {
    __shared__ float red[1024];
    int t = threadIdx.x;
    float sum = 0.f;
    for (int i = t; i < N; i += 1024) {
        float ct = ws[3 * N + i];
        float lp = ws[2 * N + i] - ct * ws[i] - ct * __logf(ws[N + i]);
        sum += (lp + 1e-6f) / (ct + 1e-6f);
    }
    red[t] = sum;
    __syncthreads();
    for (int s = 512; s >= 64; s >>= 1) {
        if (t < s) red[t] += red[t + s];
        __syncthreads();
    }
    if (t < 64) {
        float v = red[t];
#pragma unroll
        for (int off = 32; off > 0; off >>= 1) v += __shfl_xor(v, off);
        if (t == 0) out[0] = -v / (float)N;
    }
}

extern "C" void kernel_launch(void* const* d_in, const int* in_sizes, int n_in,
                              void* d_out, int out_size, void* d_ws, size_t ws_size,
                              hipStream_t stream) {
    const float* feat = (const float*)d_in[0];
    const int* labels = (const int*)d_in[1];
    float* ws = (float*)d_ws;
    unsigned short* cf = (unsigned short*)((float*)d_ws + 4 * N);
    float* out = (float*)d_out;

    init_kernel<<<N / 16, 256, 0, stream>>>(feat, ws, cf);
    pair_kernel<<<2048, 256, 0, stream>>>(cf, labels, ws);
    final_kernel<<<1, 1024, 0, stream>>>(ws, out);
}

// Round 5
// 34.079 us; speedup vs baseline: 1.3835x; 1.3835x over previous
//
#include <hip/hip_runtime.h>
#include <math.h>

#define N 4096
#define BSZ 2048
#define D 128

typedef __bf16 bf16x8 __attribute__((ext_vector_type(8)));
typedef float f32x4 __attribute__((ext_vector_type(4)));
typedef unsigned short u16x8 __attribute__((ext_vector_type(8)));

// cf[i] = features[i % bsz, i / bsz, :]  (view-major stacking)
__device__ __forceinline__ int rowbase(int i) {
    return (i & (BSZ - 1)) * (2 * D) + (i >> 11) * D;
}

__device__ __forceinline__ unsigned short f2bf(float x) {
    unsigned u = __float_as_uint(x);
    return (unsigned short)((u + 0x7fffu + ((u >> 16) & 1u)) >> 16);  // RNE
}

// ws layout: floats m[0..N) S1[N..2N) sumc[2N..3N) cnt[3N..4N); then bf16 cf[N][D]
__global__ void init_kernel(const float* __restrict__ feat, float* __restrict__ ws,
                            unsigned short* __restrict__ cf) {
    int t = threadIdx.x;
    int row = blockIdx.x * 16 + (t >> 4);
    int lq = t & 15;
    const float* p = feat + rowbase(row) + lq * 8;
    float4 v0 = *(const float4*)(p);
    float4 v1 = *(const float4*)(p + 4);
    float dot = v0.x * v0.x + v0.y * v0.y + v0.z * v0.z + v0.w * v0.w
              + v1.x * v1.x + v1.y * v1.y + v1.z * v1.z + v1.w * v1.w;
#pragma unroll
    for (int off = 1; off < 16; off <<= 1) dot += __shfl_xor(dot, off);

    u16x8 u;
    u[0] = f2bf(v0.x); u[1] = f2bf(v0.y); u[2] = f2bf(v0.z); u[3] = f2bf(v0.w);
    u[4] = f2bf(v1.x); u[5] = f2bf(v1.y); u[6] = f2bf(v1.z); u[7] = f2bf(v1.w);
    *(u16x8*)(cf + row * D + lq * 8) = u;

    if (lq == 0) {
        ws[row] = fminf(fmaxf(dot, -1.f), 1.f);  // rowmax = clipped diagonal
        ws[N + row] = 0.f;
        ws[2 * N + row] = 0.f;
        ws[3 * N + row] = 0.f;
    }
}

__launch_bounds__(256)
__global__ void pair_kernel(const unsigned short* __restrict__ cf,
                            const int* __restrict__ labels, float* __restrict__ ws) {
    __shared__ float labIf[128], labJf[128];
    __shared__ float mI[128];

    const int t = threadIdx.x;
    const int bi = blockIdx.x >> 5;   // 32x32 grid of 128x128 tiles
    const int bj = blockIdx.x & 31;
    const int i0 = bi * 128, j0 = bj * 128;

    if (t < 128) {
        labIf[t] = (float)labels[(i0 + t) & (BSZ - 1)];
        mI[t] = ws[i0 + t];
    } else {
        int u = t - 128;
        labJf[u] = (float)labels[(j0 + u) & (BSZ - 1)];
    }
    __syncthreads();

    const int wid = t >> 6, lane = t & 63;
    const int wp = wid >> 1, wq = wid & 1;      // wp: I half, wq: J half
    const int lrow = lane & 15, lk = (lane >> 4) * 8;

    // SWAPPED operands: A = J rows, B = I rows -> D[row=J][col=I]
    const unsigned short* A0 = cf + (size_t)(j0 + wq * 64 + lrow) * D + lk;
    const unsigned short* B0 = cf + (size_t)(i0 + wp * 64 + lrow) * D + lk;

    f32x4 acc[4][4] = {};   // [ar: J fragment][ac: I fragment]
#pragma unroll
    for (int ks = 0; ks < 4; ++ks) {
        bf16x8 a[4], b[4];
#pragma unroll
        for (int r = 0; r < 4; ++r) a[r] = *(const bf16x8*)(A0 + r * 16 * D + ks * 32);
#pragma unroll
        for (int c = 0; c < 4; ++c) b[c] = *(const bf16x8*)(B0 + c * 16 * D + ks * 32);
#pragma unroll
        for (int r = 0; r < 4; ++r)
#pragma unroll
            for (int c = 0; c < 4; ++c)
                acc[r][c] = __builtin_amdgcn_mfma_f32_16x16x32_bf16(a[r], b[c], acc[r][c], 0, 0, 0);
    }

    // per-lane J labels (float): jr_local = wq*64 + ar*16 + (lane>>4)*4 + rg
    const int jbl = wq * 64 + ((lane >> 4) << 2);
    float lj[16];
#pragma unroll
    for (int ar = 0; ar < 4; ++ar)
#pragma unroll
        for (int rg = 0; rg < 4; ++rg)
            lj[ar * 4 + rg] = labJf[jbl + ar * 16 + rg];

    const bool hasDiag = (bi == bj);

#pragma unroll
    for (int ac = 0; ac < 4; ++ac) {
        const int ri = wp * 64 + ac * 16 + lrow;   // I index (lane-local)
        const int gi = i0 + ri;
        const float li = labIf[ri];
        const float m = mI[ri];
        const int dg = hasDiag ? (ri - jbl) : -1;  // diag when dg == ar*16+rg
        float s1 = 0.f, sc = 0.f, ct = 0.f;
#pragma unroll
        for (int ar = 0; ar < 4; ++ar) {
#pragma unroll
            for (int rg = 0; rg < 4; ++rg) {
                float c = __builtin_amdgcn_fmed3f(acc[ar][ac][rg], -1.f, 1.f);
                float distf = li - lj[ar * 4 + rg];
                // phi = (1 - dist/100)*pi rad -> rev = 0.5 - dist/200 in [0.005,0.995]
                float rev = fmaf(distf, -0.005f, 0.5f);
                float cph = __builtin_amdgcn_cosf(rev);
                float sph = __builtin_fabsf(__builtin_amdgcn_sinf(rev));
                float st = __builtin_amdgcn_sqrtf(fmaf(-c, c, 1.000001f));
                float nl = fmaf(c, cph, -st * sph);
                bool pos = (distf == 0.f);
                bool diag = (dg == ar * 16 + rg);
                float logit = pos ? (c - m) : nl;
                float e = diag ? 0.f : __expf(logit);
                float pf = (pos && !diag) ? 1.f : 0.f;
                s1 += e;
                sc = fmaf(pf, c, sc);
                ct += pf;
            }
        }
        // combine the 4 lane-groups that share gi (lane&15): xor 16, then 32
        s1 += __shfl_xor(s1, 16); s1 += __shfl_xor(s1, 32);
        sc += __shfl_xor(sc, 16); sc += __shfl_xor(sc, 32);
        ct += __shfl_xor(ct, 16); ct += __shfl_xor(ct, 32);
        if (lane < 16) {
            atomicAdd(&ws[N + gi], s1);
            atomicAdd(&ws[2 * N + gi], sc);
            atomicAdd(&ws[3 * N + gi], ct);
        }
    }
}

__global__ void final_kernel(const float* __restrict__ ws, float* __restrict__ out) {
    __shared__ float red[1024];
    int t = threadIdx.x;
    float sum = 0.f;
    for (int i = t; i < N; i += 1024) {
        float ct = ws[3 * N + i];
        float lp = ws[2 * N + i] - ct * ws[i] - ct * __logf(ws[N + i]);
        sum += (lp + 1e-6f) / (ct + 1e-6f);
    }
    red[t] = sum;
    __syncthreads();
    for (int s = 512; s >= 64; s >>= 1) {
        if (t < s) red[t] += red[t + s];
        __syncthreads();
    }
    if (t < 64) {
        float v = red[t];
#pragma unroll
        for (int off = 32; off > 0; off >>= 1) v += __shfl_xor(v, off);
        if (t == 0) out[0] = -v / (float)N;
    }
}

extern "C" void kernel_launch(void* const* d_in, const int* in_sizes, int n_in,
                              void* d_out, int out_size, void* d_ws, size_t ws_size,
                              hipStream_t stream) {
    const float* feat = (const float*)d_in[0];
    const int* labels = (const int*)d_in[1];
    float* ws = (float*)d_ws;
    unsigned short* cf = (unsigned short*)((float*)d_ws + 4 * N);
    float* out = (float*)d_out;

    init_kernel<<<N / 16, 256, 0, stream>>>(feat, ws, cf);
    pair_kernel<<<1024, 256, 0, stream>>>(cf, labels, ws);
    final_kernel<<<1, 1024, 0, stream>>>(ws, out);
}